// Round 1
// baseline (4878.542 us; speedup 1.0000x reference)
//
#include <hip/hip_runtime.h>

#define N_TOK 131072
#define DIM   256
#define KCB   1024

#define RT   128   // rows per block (argmin kernel)
#define KT   128   // codebook entries per chunk
#define DST  32    // d-slice staged in LDS
#define LSTR 36    // padded LDS row stride (floats): 144 B, 16B-aligned, bank-skewed

// Bit-exact replica of numpy pairwise_sum over 128 contiguous floats of x*x:
// r[j] = sq[j]; for i=8..120 step 8: r[j] += sq[i+j];
// result = ((r0+r1)+(r2+r3))+((r4+r5)+(r6+r7))
// Squares are rounded to fp32 BEFORE summation (contract off blocks fma fusion).
__device__ __forceinline__ float np_sumsq_128(const float* __restrict__ p) {
#pragma clang fp contract(off)
  float4 a = *(const float4*)(p);
  float4 b = *(const float4*)(p + 4);
  float r0 = a.x * a.x, r1 = a.y * a.y, r2 = a.z * a.z, r3 = a.w * a.w;
  float r4 = b.x * b.x, r5 = b.y * b.y, r6 = b.z * b.z, r7 = b.w * b.w;
  for (int i = 8; i < 128; i += 8) {
    float4 c = *(const float4*)(p + i);
    float4 d = *(const float4*)(p + i + 4);
    r0 += c.x * c.x; r1 += c.y * c.y; r2 += c.z * c.z; r3 += c.w * c.w;
    r4 += d.x * d.x; r5 += d.y * d.y; r6 += d.z * d.z; r7 += d.w * d.w;
  }
  return ((r0 + r1) + (r2 + r3)) + ((r4 + r5) + (r6 + r7));
}

// K0: per-code ||c||^2 (numpy order: pairwise(0..127) + pairwise(128..255)),
// plus zero the fp64 loss accumulator (ws is re-poisoned 0xAA before each call).
__global__ void prep_kernel(const float* __restrict__ cb, float* __restrict__ cc,
                            double* __restrict__ loss_acc) {
  int k = blockIdx.x * blockDim.x + threadIdx.x;
  if (k == 0) *loss_acc = 0.0;
  if (k < KCB) {
    const float* p = cb + (long)k * DIM;
    cc[k] = np_sumsq_128(p) + np_sumsq_128(p + 128);
  }
}

// K1: distance + argmin. 128 rows/block, all K=1024, 8x8 register blocking.
__global__ __launch_bounds__(256, 3)
void argmin_kernel(const float* __restrict__ z, const float* __restrict__ cb,
                   const float* __restrict__ cc, float* __restrict__ ids_f) {
  __shared__ float z_s[RT * LSTR];
  __shared__ float c_s[RT * LSTR];
  __shared__ float zz_s[RT];
  __shared__ float zz_half[RT][2];

  const int t  = threadIdx.x;
  const int ti = t >> 4;   // 0..15 row group
  const int tj = t & 15;   // 0..15 k group
  const long rowbase = (long)blockIdx.x * RT;

  // ||z_row||^2, numpy order: 2 threads per row (one per 128-half)
  {
    int r = t >> 1, h = t & 1;
    zz_half[r][h] = np_sumsq_128(z + (rowbase + r) * DIM + h * 128);
  }
  __syncthreads();
  if (t < RT) zz_s[t] = zz_half[t][0] + zz_half[t][1];
  // visibility of zz_s guaranteed by the staging-loop barrier below

  float bestd[8];
  int   bestk[8];
#pragma unroll
  for (int i = 0; i < 8; ++i) { bestd[i] = __builtin_inff(); bestk[i] = 0; }

  for (int kt = 0; kt < 8; ++kt) {
    float acc[8][8];
#pragma unroll
    for (int a = 0; a < 8; ++a)
#pragma unroll
      for (int b = 0; b < 8; ++b) acc[a][b] = 0.0f;

    for (int ds = 0; ds < 8; ++ds) {
      __syncthreads();   // previous slice fully consumed
      // stage z[128][32] and c[128][32]; 4 float4 each per thread, coalesced
#pragma unroll
      for (int q = 0; q < 4; ++q) {
        int f  = q * 256 + t;
        int r  = f >> 3;
        int dq = (f & 7) << 2;
        float4 vz = *(const float4*)(z + (rowbase + r) * DIM + ds * DST + dq);
        *(float4*)(&z_s[r * LSTR + dq]) = vz;
        float4 vc = *(const float4*)(cb + (long)(kt * KT + r) * DIM + ds * DST + dq);
        *(float4*)(&c_s[r * LSTR + dq]) = vc;
      }
      __syncthreads();
      // 32 d's, 2 at a time: 16 ds_read_b64 feed 128 fmaf
#pragma unroll
      for (int d2 = 0; d2 < DST; d2 += 2) {
        float2 zf[8], cf[8];
#pragma unroll
        for (int rr = 0; rr < 8; ++rr)
          zf[rr] = *(const float2*)(&z_s[(ti + 16 * rr) * LSTR + d2]);
#pragma unroll
        for (int kk = 0; kk < 8; ++kk)
          cf[kk] = *(const float2*)(&c_s[(tj + 16 * kk) * LSTR + d2]);
#pragma unroll
        for (int rr = 0; rr < 8; ++rr)
#pragma unroll
          for (int kk = 0; kk < 8; ++kk) {
            acc[rr][kk] = fmaf(zf[rr].x, cf[kk].x, acc[rr][kk]);
            acc[rr][kk] = fmaf(zf[rr].y, cf[kk].y, acc[rr][kk]);
          }
      }
    }
    // chunk epilogue: d = (zz - 2*dot) + cc, running argmin (k ascending -> '<' keeps lowest)
#pragma unroll
    for (int rr = 0; rr < 8; ++rr) {
      float zz = zz_s[ti + 16 * rr];
#pragma unroll
      for (int kk = 0; kk < 8; ++kk) {
        int k = kt * KT + tj + 16 * kk;
        float dd = (zz - 2.0f * acc[rr][kk]) + cc[k];
        if (dd < bestd[rr]) { bestd[rr] = dd; bestk[rr] = k; }
      }
    }
  }

  // cross-thread reduction per row (16 tj candidates), tie-break to lowest k
  __syncthreads();
  float* red_d = z_s;          // alias: 128*16 floats
  int*   red_k = (int*)c_s;    // alias: 128*16 ints
#pragma unroll
  for (int rr = 0; rr < 8; ++rr) {
    int r = ti + 16 * rr;
    red_d[r * 16 + tj] = bestd[rr];
    red_k[r * 16 + tj] = bestk[rr];
  }
  __syncthreads();
  if (t < RT) {
    float bd = red_d[t * 16];
    int   bk = red_k[t * 16];
#pragma unroll
    for (int j = 1; j < 16; ++j) {
      float dj = red_d[t * 16 + j];
      int   kj = red_k[t * 16 + j];
      if (dj < bd || (dj == bd && kj < bk)) { bd = dj; bk = kj; }
    }
    ids_f[rowbase + t] = (float)bk;
  }
}

// K2: out0 = z, out1 = codebook[ids], fp64 partial sum of (zq - z)^2
__global__ void output_kernel(const float* __restrict__ z, const float* __restrict__ cb,
                              const float* __restrict__ ids_f,
                              float* __restrict__ out_z, float* __restrict__ out_zq,
                              double* __restrict__ loss_acc) {
  __shared__ double red[4];
  double acc = 0.0;
  const long total4 = (long)N_TOK * DIM / 4;
  long idx    = (long)blockIdx.x * blockDim.x + threadIdx.x;
  long stride = (long)gridDim.x * blockDim.x;
  for (long i = idx; i < total4; i += stride) {
    long e = i * 4;
    long r = e >> 8;
    int  k = (int)ids_f[r];
    float4 vz = *(const float4*)(z + e);
    float4 vc = *(const float4*)(cb + (long)k * DIM + (e & 255));
    *(float4*)(out_z + e)  = vz;
    *(float4*)(out_zq + e) = vc;
    float d0 = vc.x - vz.x, d1 = vc.y - vz.y, d2 = vc.z - vz.z, d3 = vc.w - vz.w;
    acc += (double)(d0 * d0) + (double)(d1 * d1) + (double)(d2 * d2) + (double)(d3 * d3);
  }
  // wave reduce (64 lanes)
#pragma unroll
  for (int off = 32; off > 0; off >>= 1) acc += __shfl_down(acc, off, 64);
  int lane = threadIdx.x & 63, w = threadIdx.x >> 6;
  if (lane == 0) red[w] = acc;
  __syncthreads();
  if (threadIdx.x == 0) {
    double s = (red[0] + red[1]) + (red[2] + red[3]);
    atomicAdd(loss_acc, s);
  }
}

// K3: loss = 1.25 * mean((zq - z)^2)
__global__ void finalize_kernel(const double* __restrict__ loss_acc,
                                float* __restrict__ out_loss) {
  if (threadIdx.x == 0) {
    double mean = *loss_acc / (double)((long)N_TOK * DIM);
    out_loss[0] = (float)(1.25 * mean);
  }
}

extern "C" void kernel_launch(void* const* d_in, const int* in_sizes, int n_in,
                              void* d_out, int out_size, void* d_ws, size_t ws_size,
                              hipStream_t stream) {
  const float* z  = (const float*)d_in[0];
  const float* cb = (const float*)d_in[1];
  float* out      = (float*)d_out;
  float* out_z    = out;                              // [N, D]
  float* out_zq   = out + (long)N_TOK * DIM;          // [N, D]
  float* out_ids  = out_zq + (long)N_TOK * DIM;       // [N] as fp32
  float* out_loss = out_ids + N_TOK;                  // [1]

  double* loss_acc = (double*)d_ws;                   // 8 B
  float*  cc       = (float*)((char*)d_ws + 16);      // 4 KB

  prep_kernel<<<4, 256, 0, stream>>>(cb, cc, loss_acc);
  argmin_kernel<<<N_TOK / RT, 256, 0, stream>>>(z, cb, cc, out_ids);
  output_kernel<<<2048, 256, 0, stream>>>(z, cb, out_ids, out_z, out_zq, loss_acc);
  finalize_kernel<<<1, 64, 0, stream>>>(loss_acc, out_loss);
}

// Round 2
// 1386.697 us; speedup vs baseline: 3.5181x; 3.5181x over previous
//
#include <hip/hip_runtime.h>

#define N_TOK 131072
#define DIM   256
#define KCB   1024

#define RT   128   // rows per block (argmin kernel)
#define KT   128   // codebook entries per chunk
#define DST  32    // d-slice staged in LDS
#define LSTR 36    // padded LDS row stride (floats): 144 B, 16B-aligned, bank-skewed

// Bit-exact replica of numpy pairwise_sum over 128 contiguous floats of x*x:
// r[j] = sq[j]; for i=8..120 step 8: r[j] += sq[i+j];
// result = ((r0+r1)+(r2+r3))+((r4+r5)+(r6+r7))
// Squares are rounded to fp32 BEFORE summation (contract off blocks fma fusion).
__device__ __forceinline__ float np_sumsq_128(const float* __restrict__ p) {
#pragma clang fp contract(off)
  float4 a = *(const float4*)(p);
  float4 b = *(const float4*)(p + 4);
  float r0 = a.x * a.x, r1 = a.y * a.y, r2 = a.z * a.z, r3 = a.w * a.w;
  float r4 = b.x * b.x, r5 = b.y * b.y, r6 = b.z * b.z, r7 = b.w * b.w;
  for (int i = 8; i < 128; i += 8) {
    float4 c = *(const float4*)(p + i);
    float4 d = *(const float4*)(p + i + 4);
    r0 += c.x * c.x; r1 += c.y * c.y; r2 += c.z * c.z; r3 += c.w * c.w;
    r4 += d.x * d.x; r5 += d.y * d.y; r6 += d.z * d.z; r7 += d.w * d.w;
  }
  return ((r0 + r1) + (r2 + r3)) + ((r4 + r5) + (r6 + r7));
}

// K0: per-code ||c||^2 (numpy order: pairwise(0..127) + pairwise(128..255)),
// plus zero the fp64 loss accumulator (ws is re-poisoned 0xAA before each call).
__global__ void prep_kernel(const float* __restrict__ cb, float* __restrict__ cc,
                            double* __restrict__ loss_acc) {
  int k = blockIdx.x * blockDim.x + threadIdx.x;
  if (k == 0) *loss_acc = 0.0;
  if (k < KCB) {
    const float* p = cb + (long)k * DIM;
    cc[k] = np_sumsq_128(p) + np_sumsq_128(p + 128);
  }
}

// K1: distance + argmin. 128 rows/block, all K=1024, 8x8 register blocking.
// launch_bounds(256,2): VGPR cap 256 — the (256,3) variant spilled acc[8][8]
// to scratch (VGPR_Count=84, 9.3 GB scratch writes, 4788 us). Needs ~130 live.
__global__ __launch_bounds__(256, 2)
void argmin_kernel(const float* __restrict__ z, const float* __restrict__ cb,
                   const float* __restrict__ cc, float* __restrict__ ids_f) {
  __shared__ float z_s[RT * LSTR];
  __shared__ float c_s[RT * LSTR];
  __shared__ float zz_s[RT];
  __shared__ float zz_half[RT][2];

  const int t  = threadIdx.x;
  const int ti = t >> 4;   // 0..15 row group
  const int tj = t & 15;   // 0..15 k group
  const long rowbase = (long)blockIdx.x * RT;

  // ||z_row||^2, numpy order: 2 threads per row (one per 128-half)
  {
    int r = t >> 1, h = t & 1;
    zz_half[r][h] = np_sumsq_128(z + (rowbase + r) * DIM + h * 128);
  }
  __syncthreads();
  if (t < RT) zz_s[t] = zz_half[t][0] + zz_half[t][1];
  // visibility of zz_s guaranteed by the staging-loop barrier below

  float bestd[8];
  int   bestk[8];
#pragma unroll
  for (int i = 0; i < 8; ++i) { bestd[i] = __builtin_inff(); bestk[i] = 0; }

  for (int kt = 0; kt < 8; ++kt) {
    float acc[8][8];
#pragma unroll
    for (int a = 0; a < 8; ++a)
#pragma unroll
      for (int b = 0; b < 8; ++b) acc[a][b] = 0.0f;

    for (int ds = 0; ds < 8; ++ds) {
      __syncthreads();   // previous slice fully consumed
      // stage z[128][32] and c[128][32]; 4 float4 each per thread, coalesced
#pragma unroll
      for (int q = 0; q < 4; ++q) {
        int f  = q * 256 + t;
        int r  = f >> 3;
        int dq = (f & 7) << 2;
        float4 vz = *(const float4*)(z + (rowbase + r) * DIM + ds * DST + dq);
        *(float4*)(&z_s[r * LSTR + dq]) = vz;
        float4 vc = *(const float4*)(cb + (long)(kt * KT + r) * DIM + ds * DST + dq);
        *(float4*)(&c_s[r * LSTR + dq]) = vc;
      }
      __syncthreads();
      // 32 d's, 2 at a time: 16 ds_read_b64 feed 128 fmaf.
      // unroll 4 (not full): caps scheduler live-range ballooning that drove
      // the round-1 spill; per-acc fmaf chain order (d ascending) unchanged.
#pragma unroll 4
      for (int d2 = 0; d2 < DST; d2 += 2) {
        float2 zf[8], cf[8];
#pragma unroll
        for (int rr = 0; rr < 8; ++rr)
          zf[rr] = *(const float2*)(&z_s[(ti + 16 * rr) * LSTR + d2]);
#pragma unroll
        for (int kk = 0; kk < 8; ++kk)
          cf[kk] = *(const float2*)(&c_s[(tj + 16 * kk) * LSTR + d2]);
#pragma unroll
        for (int rr = 0; rr < 8; ++rr)
#pragma unroll
          for (int kk = 0; kk < 8; ++kk) {
            acc[rr][kk] = fmaf(zf[rr].x, cf[kk].x, acc[rr][kk]);
            acc[rr][kk] = fmaf(zf[rr].y, cf[kk].y, acc[rr][kk]);
          }
      }
    }
    // chunk epilogue: d = (zz - 2*dot) + cc, running argmin (k ascending -> '<' keeps lowest)
#pragma unroll
    for (int rr = 0; rr < 8; ++rr) {
      float zz = zz_s[ti + 16 * rr];
#pragma unroll
      for (int kk = 0; kk < 8; ++kk) {
        int k = kt * KT + tj + 16 * kk;
        float dd = (zz - 2.0f * acc[rr][kk]) + cc[k];
        if (dd < bestd[rr]) { bestd[rr] = dd; bestk[rr] = k; }
      }
    }
  }

  // cross-thread reduction per row (16 tj candidates), tie-break to lowest k
  __syncthreads();
  float* red_d = z_s;          // alias: 128*16 floats
  int*   red_k = (int*)c_s;    // alias: 128*16 ints
#pragma unroll
  for (int rr = 0; rr < 8; ++rr) {
    int r = ti + 16 * rr;
    red_d[r * 16 + tj] = bestd[rr];
    red_k[r * 16 + tj] = bestk[rr];
  }
  __syncthreads();
  if (t < RT) {
    float bd = red_d[t * 16];
    int   bk = red_k[t * 16];
#pragma unroll
    for (int j = 1; j < 16; ++j) {
      float dj = red_d[t * 16 + j];
      int   kj = red_k[t * 16 + j];
      if (dj < bd || (dj == bd && kj < bk)) { bd = dj; bk = kj; }
    }
    ids_f[rowbase + t] = (float)bk;
  }
}

// K2: out0 = z, out1 = codebook[ids], fp64 partial sum of (zq - z)^2
__global__ void output_kernel(const float* __restrict__ z, const float* __restrict__ cb,
                              const float* __restrict__ ids_f,
                              float* __restrict__ out_z, float* __restrict__ out_zq,
                              double* __restrict__ loss_acc) {
  __shared__ double red[4];
  double acc = 0.0;
  const long total4 = (long)N_TOK * DIM / 4;
  long idx    = (long)blockIdx.x * blockDim.x + threadIdx.x;
  long stride = (long)gridDim.x * blockDim.x;
  for (long i = idx; i < total4; i += stride) {
    long e = i * 4;
    long r = e >> 8;
    int  k = (int)ids_f[r];
    float4 vz = *(const float4*)(z + e);
    float4 vc = *(const float4*)(cb + (long)k * DIM + (e & 255));
    *(float4*)(out_z + e)  = vz;
    *(float4*)(out_zq + e) = vc;
    float d0 = vc.x - vz.x, d1 = vc.y - vz.y, d2 = vc.z - vz.z, d3 = vc.w - vz.w;
    acc += (double)(d0 * d0) + (double)(d1 * d1) + (double)(d2 * d2) + (double)(d3 * d3);
  }
  // wave reduce (64 lanes)
#pragma unroll
  for (int off = 32; off > 0; off >>= 1) acc += __shfl_down(acc, off, 64);
  int lane = threadIdx.x & 63, w = threadIdx.x >> 6;
  if (lane == 0) red[w] = acc;
  __syncthreads();
  if (threadIdx.x == 0) {
    double s = (red[0] + red[1]) + (red[2] + red[3]);
    atomicAdd(loss_acc, s);
  }
}

// K3: loss = 1.25 * mean((zq - z)^2)
__global__ void finalize_kernel(const double* __restrict__ loss_acc,
                                float* __restrict__ out_loss) {
  if (threadIdx.x == 0) {
    double mean = *loss_acc / (double)((long)N_TOK * DIM);
    out_loss[0] = (float)(1.25 * mean);
  }
}

extern "C" void kernel_launch(void* const* d_in, const int* in_sizes, int n_in,
                              void* d_out, int out_size, void* d_ws, size_t ws_size,
                              hipStream_t stream) {
  const float* z  = (const float*)d_in[0];
  const float* cb = (const float*)d_in[1];
  float* out      = (float*)d_out;
  float* out_z    = out;                              // [N, D]
  float* out_zq   = out + (long)N_TOK * DIM;          // [N, D]
  float* out_ids  = out_zq + (long)N_TOK * DIM;       // [N] as fp32
  float* out_loss = out_ids + N_TOK;                  // [1]

  double* loss_acc = (double*)d_ws;                   // 8 B
  float*  cc       = (float*)((char*)d_ws + 16);      // 4 KB

  prep_kernel<<<4, 256, 0, stream>>>(cb, cc, loss_acc);
  argmin_kernel<<<N_TOK / RT, 256, 0, stream>>>(z, cb, cc, out_ids);
  output_kernel<<<2048, 256, 0, stream>>>(z, cb, out_ids, out_z, out_zq, loss_acc);
  finalize_kernel<<<1, 64, 0, stream>>>(loss_acc, out_loss);
}

// Round 3
// 1024.021 us; speedup vs baseline: 4.7641x; 1.3542x over previous
//
#include <hip/hip_runtime.h>

#define N_TOK 131072
#define DIM   256
#define KCB   1024

#define RT    128          // rows per block
#define KT    128          // codes per kt chunk
#define SSTR  40           // LDS row stride in shorts (80 B, 16B-aligned, bank-skewed)
#define TAU   1.0e-3f      // candidate margin; >=5x worst-case |dd' - dd_fp32|
#define EMIT_CAP 2048

typedef __attribute__((ext_vector_type(8))) short bf16x8;
typedef __attribute__((ext_vector_type(4))) float f32x4;

// RTNE fp32 -> bf16 (finite inputs only)
__device__ __forceinline__ unsigned short bf16_rtne(float v) {
  unsigned u = __float_as_uint(v);
  return (unsigned short)((u + 0x7FFFu + ((u >> 16) & 1u)) >> 16);
}
__device__ __forceinline__ float bf16_tof(unsigned short s) {
  return __uint_as_float(((unsigned)s) << 16);
}

// Bit-exact replica of numpy pairwise_sum over 128 floats of x*x (see round 1/2).
__device__ __forceinline__ float np_sumsq_128(const float* __restrict__ p) {
#pragma clang fp contract(off)
  float4 a = *(const float4*)(p);
  float4 b = *(const float4*)(p + 4);
  float r0 = a.x * a.x, r1 = a.y * a.y, r2 = a.z * a.z, r3 = a.w * a.w;
  float r4 = b.x * b.x, r5 = b.y * b.y, r6 = b.z * b.z, r7 = b.w * b.w;
  for (int i = 8; i < 128; i += 8) {
    float4 c = *(const float4*)(p + i);
    float4 d = *(const float4*)(p + i + 4);
    r0 += c.x * c.x; r1 += c.y * c.y; r2 += c.z * c.z; r3 += c.w * c.w;
    r4 += d.x * d.x; r5 += d.y * d.y; r6 += d.z * d.z; r7 += d.w * d.w;
  }
  return ((r0 + r1) + (r2 + r3)) + ((r4 + r5) + (r6 + r7));
}

// K0a: ||c_k||^2 (same bits as rounds 1/2) + zero the fp64 loss accumulator.
__global__ void prep_cc(const float* __restrict__ cb, float* __restrict__ cc,
                        double* __restrict__ loss_acc) {
  int k = blockIdx.x * blockDim.x + threadIdx.x;
  if (k == 0) *loss_acc = 0.0;
  if (k < KCB) {
    const float* p = cb + (long)k * DIM;
    cc[k] = np_sumsq_128(p) + np_sumsq_128(p + 128);
  }
}

// K0b: split codebook into bf16 hi/lo planes.
__global__ void prep_split(const float* __restrict__ cb, short* __restrict__ ch,
                           short* __restrict__ cm) {
  int i = blockIdx.x * blockDim.x + threadIdx.x;
  if (i < KCB * DIM) {
    float v = cb[i];
    unsigned short h = bf16_rtne(v);
    ch[i] = (short)h;
    cm[i] = (short)bf16_rtne(v - bf16_tof(h));
  }
}

// K1: MFMA 3-term distance + candidate emission + exact fmaf-chain recheck.
// Final ids are bit-identical to the round-2 fp32 kernel by construction.
__global__ __launch_bounds__(256)
void argmin_kernel(const float* __restrict__ z, const float* __restrict__ cb,
                   const short* __restrict__ ch_g, const short* __restrict__ cm_g,
                   const float* __restrict__ cc_g, float* __restrict__ ids_f) {
  __shared__ short zh_s[RT * SSTR];
  __shared__ short zm_s[RT * SSTR];
  __shared__ short ch_s[KT * SSTR];
  __shared__ short cm_s[KT * SSTR];
  __shared__ float zz_s[RT];
  __shared__ float zz_half[RT][2];
  __shared__ unsigned rowmin_s[RT];   // packed fp32 bits (positive -> monotonic)
  __shared__ int kmin_s[RT];
  __shared__ unsigned emit_s[EMIT_CAP];
  __shared__ int emit_cnt;

  const int t    = threadIdx.x;
  const int lane = t & 63;
  const int w    = t >> 6;       // wave 0..3, owns rows 32w..32w+31
  const int l15  = lane & 15;
  const int qd   = lane >> 4;    // quad 0..3
  const long rowbase = (long)blockIdx.x * RT;

  // ||z_row||^2, numpy order (identical bits to round 2)
  {
    int r = t >> 1, h = t & 1;
    zz_half[r][h] = np_sumsq_128(z + (rowbase + r) * DIM + h * 128);
  }
  if (t < RT) { rowmin_s[t] = 0xFFFFFFFFu; kmin_s[t] = 0x7FFFFFFF; }
  if (t == 0) emit_cnt = 0;
  __syncthreads();
  if (t < RT) zz_s[t] = zz_half[t][0] + zz_half[t][1];
  // visibility of zz_s: guaranteed by staging barriers before first use

#pragma clang loop unroll(disable)
  for (int kt = 0; kt < 8; ++kt) {
    f32x4 acc[2][8];
#pragma unroll
    for (int m = 0; m < 2; ++m)
#pragma unroll
      for (int c = 0; c < 8; ++c) acc[m][c] = (f32x4){0.f, 0.f, 0.f, 0.f};

#pragma clang loop unroll(disable)
    for (int ds = 0; ds < 8; ++ds) {
      __syncthreads();   // previous slice fully consumed
      // stage z slice [128 rows x 32 d] -> zh_s/zm_s (convert on the fly)
#pragma unroll
      for (int q = 0; q < 4; ++q) {
        int f = q * 256 + t;
        int r = f >> 3, d4 = f & 7;
        float4 v = *(const float4*)(z + (rowbase + r) * DIM + ds * 32 + d4 * 4);
        short4 hv, mv;
        hv.x = (short)bf16_rtne(v.x); mv.x = (short)bf16_rtne(v.x - bf16_tof(hv.x));
        hv.y = (short)bf16_rtne(v.y); mv.y = (short)bf16_rtne(v.y - bf16_tof(hv.y));
        hv.z = (short)bf16_rtne(v.z); mv.z = (short)bf16_rtne(v.z - bf16_tof(hv.z));
        hv.w = (short)bf16_rtne(v.w); mv.w = (short)bf16_rtne(v.w - bf16_tof(hv.w));
        *(short4*)&zh_s[r * SSTR + d4 * 4] = hv;
        *(short4*)&zm_s[r * SSTR + d4 * 4] = mv;
      }
      // stage codebook slice [128 k x 32 d] from pre-split planes (pure copy)
#pragma unroll
      for (int q = 0; q < 2; ++q) {
        int f = q * 256 + t;
        int r = f >> 2, d8 = f & 3;
        long gofs = (long)(kt * KT + r) * DIM + ds * 32 + d8 * 8;
        *(int4*)&ch_s[r * SSTR + d8 * 8] = *(const int4*)(ch_g + gofs);
        *(int4*)&cm_s[r * SSTR + d8 * 8] = *(const int4*)(cm_g + gofs);
      }
      __syncthreads();
      // fragments: A[m = lane&15][k = quad*8+j], B symmetric (codes as rows)
      bf16x8 a_h[2], a_m[2];
#pragma unroll
      for (int m = 0; m < 2; ++m) {
        int row = 32 * w + 16 * m + l15;
        a_h[m] = *(const bf16x8*)&zh_s[row * SSTR + qd * 8];
        a_m[m] = *(const bf16x8*)&zm_s[row * SSTR + qd * 8];
      }
#pragma unroll
      for (int c = 0; c < 8; ++c) {
        int kr = 16 * c + l15;
        bf16x8 b_h = *(const bf16x8*)&ch_s[kr * SSTR + qd * 8];
        bf16x8 b_m = *(const bf16x8*)&cm_s[kr * SSTR + qd * 8];
#pragma unroll
        for (int m = 0; m < 2; ++m) {
          acc[m][c] = __builtin_amdgcn_mfma_f32_16x16x32_bf16(a_h[m], b_h, acc[m][c], 0, 0, 0);
          acc[m][c] = __builtin_amdgcn_mfma_f32_16x16x32_bf16(a_h[m], b_m, acc[m][c], 0, 0, 0);
          acc[m][c] = __builtin_amdgcn_mfma_f32_16x16x32_bf16(a_m[m], b_h, acc[m][c], 0, 0, 0);
        }
      }
    }

    // ---- kt epilogue: update per-row running min of dd' ----
    // C/D layout: col = lane&15 (code), row = quad*4 + reg (within 16-tile)
    float rmin[2][4];
#pragma unroll
    for (int m = 0; m < 2; ++m)
#pragma unroll
      for (int rg = 0; rg < 4; ++rg) {
        int row = 32 * w + 16 * m + 4 * qd + rg;
        float zz = zz_s[row];
        float mn = __builtin_inff();
#pragma unroll
        for (int c = 0; c < 8; ++c) {
          float dv = (zz - 2.0f * acc[m][c][rg]) + cc_g[kt * KT + 16 * c + l15];
          mn = fminf(mn, dv);
        }
        rmin[m][rg] = mn;
      }
#pragma unroll
    for (int off = 1; off < 16; off <<= 1)
#pragma unroll
      for (int m = 0; m < 2; ++m)
#pragma unroll
        for (int rg = 0; rg < 4; ++rg)
          rmin[m][rg] = fminf(rmin[m][rg], __shfl_xor(rmin[m][rg], off, 64));
    if (l15 == 0) {
#pragma unroll
      for (int m = 0; m < 2; ++m)
#pragma unroll
        for (int rg = 0; rg < 4; ++rg)
          atomicMin(&rowmin_s[32 * w + 16 * m + 4 * qd + rg], __float_as_uint(rmin[m][rg]));
    }
    __syncthreads();
    // ---- emission: dd' <= running_min + TAU  (superset of exact-argmin+ties) ----
#pragma unroll
    for (int m = 0; m < 2; ++m)
#pragma unroll
      for (int rg = 0; rg < 4; ++rg) {
        int row = 32 * w + 16 * m + 4 * qd + rg;
        float th = __uint_as_float(rowmin_s[row]) + TAU;
        float zz = zz_s[row];
#pragma unroll
        for (int c = 0; c < 8; ++c) {
          int k = kt * KT + 16 * c + l15;
          float dv = (zz - 2.0f * acc[m][c][rg]) + cc_g[k];
          if (dv <= th) {
            int idx = atomicAdd(&emit_cnt, 1);
            if (idx < EMIT_CAP) emit_s[idx] = ((unsigned)row << 10) | (unsigned)k;
          }
        }
      }
    // next kt's staging barrier separates emission from further rowmin updates
  }

  // ---- exact recheck of candidates: reproduces round-2 fp32 bits exactly ----
  __syncthreads();
  int cnt = emit_cnt;
  bool over = cnt > EMIT_CAP;
  if (t < RT) rowmin_s[t] = 0xFFFFFFFFu;
  __syncthreads();

  if (!over) {
    unsigned mydd[8]; int myn[8], myk[8]; int mc = 0;
    for (int p = t; p < cnt; p += 256) {
      unsigned e = emit_s[p];
      int n = (int)(e >> 10), k = (int)(e & 1023);
      const float* zp = z + (rowbase + n) * DIM;
      const float* cp = cb + (long)k * DIM;
      float dot = 0.f;
      for (int d = 0; d < DIM; d += 4) {   // sequential fmaf chain, d ascending
        float4 zv = *(const float4*)(zp + d);
        float4 cv = *(const float4*)(cp + d);
        dot = fmaf(zv.x, cv.x, dot); dot = fmaf(zv.y, cv.y, dot);
        dot = fmaf(zv.z, cv.z, dot); dot = fmaf(zv.w, cv.w, dot);
      }
      float dd = (zz_s[n] - 2.0f * dot) + cc_g[k];
      mydd[mc] = __float_as_uint(dd); myn[mc] = n; myk[mc] = k; ++mc;
      atomicMin(&rowmin_s[n], __float_as_uint(dd));
    }
    __syncthreads();
    for (int i = 0; i < mc; ++i)
      if (mydd[i] == rowmin_s[myn[i]]) atomicMin(&kmin_s[myn[i]], myk[i]);
  } else {
    // pathological overflow fallback (never expected): exact full scan
    for (int p = t; p < RT * KCB; p += 256) {
      int n = p >> 10, k = p & 1023;
      const float* zp = z + (rowbase + n) * DIM;
      const float* cp = cb + (long)k * DIM;
      float dot = 0.f;
      for (int d = 0; d < DIM; d += 4) {
        float4 zv = *(const float4*)(zp + d);
        float4 cv = *(const float4*)(cp + d);
        dot = fmaf(zv.x, cv.x, dot); dot = fmaf(zv.y, cv.y, dot);
        dot = fmaf(zv.z, cv.z, dot); dot = fmaf(zv.w, cv.w, dot);
      }
      float dd = (zz_s[n] - 2.0f * dot) + cc_g[k];
      atomicMin(&rowmin_s[n], __float_as_uint(dd));
    }
    __syncthreads();
    for (int p = t; p < RT * KCB; p += 256) {
      int n = p >> 10, k = p & 1023;
      const float* zp = z + (rowbase + n) * DIM;
      const float* cp = cb + (long)k * DIM;
      float dot = 0.f;
      for (int d = 0; d < DIM; d += 4) {
        float4 zv = *(const float4*)(zp + d);
        float4 cv = *(const float4*)(cp + d);
        dot = fmaf(zv.x, cv.x, dot); dot = fmaf(zv.y, cv.y, dot);
        dot = fmaf(zv.z, cv.z, dot); dot = fmaf(zv.w, cv.w, dot);
      }
      float dd = (zz_s[n] - 2.0f * dot) + cc_g[k];
      if (__float_as_uint(dd) == rowmin_s[n]) atomicMin(&kmin_s[n], k);
    }
  }
  __syncthreads();
  if (t < RT) ids_f[rowbase + t] = (float)kmin_s[t];
}

// K2: out0 = z, out1 = codebook[ids], fp64 partial sum of (zq - z)^2
__global__ void output_kernel(const float* __restrict__ z, const float* __restrict__ cb,
                              const float* __restrict__ ids_f,
                              float* __restrict__ out_z, float* __restrict__ out_zq,
                              double* __restrict__ loss_acc) {
  __shared__ double red[4];
  double acc = 0.0;
  const long total4 = (long)N_TOK * DIM / 4;
  long idx    = (long)blockIdx.x * blockDim.x + threadIdx.x;
  long stride = (long)gridDim.x * blockDim.x;
  for (long i = idx; i < total4; i += stride) {
    long e = i * 4;
    long r = e >> 8;
    int  k = (int)ids_f[r];
    float4 vz = *(const float4*)(z + e);
    float4 vc = *(const float4*)(cb + (long)k * DIM + (e & 255));
    *(float4*)(out_z + e)  = vz;
    *(float4*)(out_zq + e) = vc;
    float d0 = vc.x - vz.x, d1 = vc.y - vz.y, d2 = vc.z - vz.z, d3 = vc.w - vz.w;
    acc += (double)(d0 * d0) + (double)(d1 * d1) + (double)(d2 * d2) + (double)(d3 * d3);
  }
#pragma unroll
  for (int off = 32; off > 0; off >>= 1) acc += __shfl_down(acc, off, 64);
  int lane = threadIdx.x & 63, wv = threadIdx.x >> 6;
  if (lane == 0) red[wv] = acc;
  __syncthreads();
  if (threadIdx.x == 0) {
    double s = (red[0] + red[1]) + (red[2] + red[3]);
    atomicAdd(loss_acc, s);
  }
}

// K3: loss = 1.25 * mean((zq - z)^2)
__global__ void finalize_kernel(const double* __restrict__ loss_acc,
                                float* __restrict__ out_loss) {
  if (threadIdx.x == 0) {
    double mean = *loss_acc / (double)((long)N_TOK * DIM);
    out_loss[0] = (float)(1.25 * mean);
  }
}

extern "C" void kernel_launch(void* const* d_in, const int* in_sizes, int n_in,
                              void* d_out, int out_size, void* d_ws, size_t ws_size,
                              hipStream_t stream) {
  const float* z  = (const float*)d_in[0];
  const float* cb = (const float*)d_in[1];
  float* out      = (float*)d_out;
  float* out_z    = out;                              // [N, D]
  float* out_zq   = out + (long)N_TOK * DIM;          // [N, D]
  float* out_ids  = out_zq + (long)N_TOK * DIM;       // [N] as fp32
  float* out_loss = out_ids + N_TOK;                  // [1]

  double* loss_acc = (double*)d_ws;                   // 8 B in ws

  // scratch inside the out_z region (dead until output_kernel overwrites it):
  // ch (512 KB) | cm (512 KB) | cc (4 KB)  -- all consumed before K2 writes out_z
  short* ch_g = (short*)((char*)d_out);
  short* cm_g = (short*)((char*)d_out + 524288);
  float* cc_g = (float*)((char*)d_out + 1048576);

  prep_cc<<<4, 256, 0, stream>>>(cb, cc_g, loss_acc);
  prep_split<<<KCB * DIM / 256, 256, 0, stream>>>(cb, ch_g, cm_g);
  argmin_kernel<<<N_TOK / RT, 256, 0, stream>>>(z, cb, ch_g, cm_g, cc_g, out_ids);
  output_kernel<<<2048, 256, 0, stream>>>(z, cb, out_ids, out_z, out_zq, loss_acc);
  finalize_kernel<<<1, 64, 0, stream>>>(loss_acc, out_loss);
}